// Round 6
// baseline (547.405 us; speedup 1.0000x reference)
//
#include <hip/hip_runtime.h>
#include <cstddef>
#include <cstdint>

static constexpr int IN_C  = 128;
static constexpr float BN_EPS = 1e-5f;
static constexpr int OUT_C = 64;

// counting-sort geometry (N=50000, E=800000)
static constexpr int CS_C = 32;       // edge chunks
static constexpr int CS_R = 8;        // node ranges
static constexpr int CS_RANGE = 6250; // max nodes per range

using bf16x8 = __attribute__((ext_vector_type(8))) short;
using f32x4  = __attribute__((ext_vector_type(4))) float;

__device__ __forceinline__ ushort f2bf(float f) {
    uint u = __float_as_uint(f);
    u += 0x7fffu + ((u >> 16) & 1u);
    return (ushort)(u >> 16);
}
__device__ __forceinline__ uint pack2(float a, float b) {
    return (uint)f2bf(a) | ((uint)f2bf(b) << 16);
}
__device__ __forceinline__ float bf_lo(uint v) { return __uint_as_float(v << 16); }
__device__ __forceinline__ float bf_hi(uint v) { return __uint_as_float(v & 0xffff0000u); }

// LDS bank-conflict-avoiding column swizzle for [row][4 groups of 8 bf16].
__device__ __forceinline__ int swz8(int row, int g) { return (g ^ ((row >> 1) & 3)) * 8; }

// hwreg(HW_REG_XCC_ID=20, offset 0, size 32) -> low 4 bits = XCC id (m09)
#define XCC_HWREG_ENC ((31 << 11) | 20)

// ---------------------------------------------------------------------------
// K1: per-(range,chunk) LDS histograms of src and dst (ushort partials) +
// block-specialized tail: x -> x_bf convert and weight transpose/convert.
__global__ __launch_bounds__(1024) void hist_conv_k(
    const int* __restrict__ src, const int* __restrict__ dst,
    ushort* __restrict__ hsrc_part, ushort* __restrict__ hdst_part,
    int N, int E, int chunk, int range, int nb_hist, int nb_x,
    const float* __restrict__ x, ushort* __restrict__ xb,
    const float* __restrict__ W1_0, const float* __restrict__ W1_1,
    const float* __restrict__ b1,
    const float* __restrict__ Wmu_0, const float* __restrict__ Wmu_1,
    const float* __restrict__ b_mu,
    const float* __restrict__ Wls_0, const float* __restrict__ Wls_1,
    const float* __restrict__ b_ls,
    ushort* __restrict__ Wt1, ushort* __restrict__ Wt2,
    float* __restrict__ bias1, float* __restrict__ bias2) {
    __shared__ int hs_[CS_RANGE];
    __shared__ int hd_[CS_RANGE];
    int bid = blockIdx.x;
    if (bid < nb_hist) {
        int c = bid & (CS_C - 1);
        int r = bid / CS_C;
        int base = r * range;
        int hi = min(base + range, N);
        int rsz = hi - base;
        for (int j = threadIdx.x; j < rsz; j += 1024) { hs_[j] = 0; hd_[j] = 0; }
        __syncthreads();
        int e0 = c * chunk, e1 = min(e0 + chunk, E);
        for (int i = e0 + threadIdx.x; i < e1; i += 1024) {
            int s = src[i];
            if (s >= base && s < hi) atomicAdd(&hs_[s - base], 1);
            int t = dst[i];
            if (t >= base && t < hi) atomicAdd(&hd_[t - base], 1);
        }
        __syncthreads();
        for (int j = threadIdx.x; j < rsz; j += 1024) {
            hsrc_part[(size_t)c * N + base + j] = (ushort)hs_[j];
            hdst_part[(size_t)c * N + base + j] = (ushort)hd_[j];
        }
    } else if (bid < nb_hist + nb_x) {
        int i = (bid - nb_hist) * 1024 + threadIdx.x;   // over N*64 float2
        if (i < N * 64) {
            float2 v = ((const float2*)x)[i];
            ((uint*)xb)[i] = pack2(v.x, v.y);
        }
    } else {
        int idx = (bid - nb_hist - nb_x) * 1024 + threadIdx.x;  // 65536 weights
        int which = idx >> 15;
        int c = (idx >> 8) & 127;
        int k = idx & 255;
        if (which == 0) {
            float v = (k < 128) ? W1_0[k * 128 + c] : W1_1[(k - 128) * 128 + c];
            Wt1[c * 256 + k] = f2bf(v);
            if (k == 0) bias1[c] = b1[c];
        } else {
            float v;
            if (c < 64) v = (k < 128) ? Wmu_0[k * 64 + c] : Wmu_1[(k - 128) * 64 + c];
            else        v = (k < 128) ? Wls_0[k * 64 + (c - 64)] : Wls_1[(k - 128) * 64 + (c - 64)];
            Wt2[c * 256 + k] = f2bf(v);
            if (k == 0) bias2[c] = (c < 64) ? b_mu[c] : b_ls[c - 64];
        }
    }
}

// K2: full-chip reduce over chunks -> dinv, cnt_dst, per-block sums.
// Also zeroes stats and the prop1 work counters (ctrA).
__global__ __launch_bounds__(256) void count_k(
    const ushort* __restrict__ hsrc_part, const ushort* __restrict__ hdst_part,
    float* __restrict__ dinv, int* __restrict__ cnt_dst,
    int* __restrict__ bsum, float* __restrict__ stats,
    int* __restrict__ ctrA, int N) {
    __shared__ int sw[4];
    int tid = threadIdx.x;
    if (blockIdx.x == 0) {
        stats[tid] = 0.f;   // 256 floats
        if (tid < 16) ctrA[tid] = 0;
    }
    int v = blockIdx.x * 256 + tid;
    int b = 0;
    if (v < N) {
        int a = 0;
        for (int c = 0; c < CS_C; ++c) {
            a += hsrc_part[(size_t)c * N + v];
            b += hdst_part[(size_t)c * N + v];
        }
        dinv[v] = (a > 0) ? rsqrtf((float)a) : 0.f;
        cnt_dst[v] = b;
    }
    int t = b;
    #pragma unroll
    for (int off = 1; off < 64; off <<= 1) t += __shfl_xor(t, off, 64);
    if ((tid & 63) == 0) sw[tid >> 6] = t;
    __syncthreads();
    if (tid == 0) bsum[blockIdx.x] = sw[0] + sw[1] + sw[2] + sw[3];
}

// K3: row_ptr + scatter offsets. Each block recomputes its own exclusive
// prefix over bsum (nb<=256 ints) -- absorbs a dedicated scan launch.
__global__ __launch_bounds__(256) void phase3_k(
    const int* __restrict__ cnt, const int* __restrict__ bsum,
    int* __restrict__ row_ptr, const ushort* __restrict__ hdst_part,
    int* __restrict__ offs, int n, int nb) {
    __shared__ int sbp[4];
    __shared__ int swv[4];
    int tid = threadIdx.x;
    int lane = tid & 63, wave = tid >> 6;
    int bv = (tid < nb && tid < (int)blockIdx.x) ? bsum[tid] : 0;
    int t = bv;
    #pragma unroll
    for (int off = 1; off < 64; off <<= 1) t += __shfl_xor(t, off, 64);
    if (lane == 0) sbp[wave] = t;
    int v = blockIdx.x * 256 + tid;
    int c = (v < n) ? cnt[v] : 0;
    int s = c;
    #pragma unroll
    for (int off = 1; off < 64; off <<= 1) {
        int u = __shfl_up(s, off, 64);
        if (lane >= off) s += u;
    }
    if (lane == 63) swv[wave] = s;
    __syncthreads();
    int bpre = sbp[0] + sbp[1] + sbp[2] + sbp[3];
    int wexcl = 0;
    for (int w = 0; w < wave; ++w) wexcl += swv[w];
    int st = bpre + wexcl + (s - c);   // global exclusive prefix
    if (v < n) row_ptr[v + 1] = st + c;
    if (v == 0) row_ptr[0] = 0;
    int r = st;
    for (int ch = 0; ch < CS_C; ++ch) {
        size_t idx = (size_t)ch * n + v;
        if (v < n) {
            offs[idx] = r;
            r += hdst_part[idx];
        }
    }
}

// K4: scatter via LDS cursors — no global atomics. col stored as ushort
// (node ids < 65536) to halve the per-propagate col stream.
__global__ __launch_bounds__(1024) void scatter_k(
    const int* __restrict__ src, const int* __restrict__ dst,
    const int* __restrict__ off, ushort* __restrict__ col,
    int N, int E, int chunk, int range) {
    __shared__ int cur[CS_RANGE];
    int c = blockIdx.x & (CS_C - 1);
    int r = blockIdx.x / CS_C;
    int base = r * range;
    int hi = min(base + range, N);
    int rsz = hi - base;
    for (int j = threadIdx.x; j < rsz; j += 1024)
        cur[j] = off[(size_t)c * N + base + j];
    __syncthreads();
    int e0 = c * chunk, e1 = min(e0 + chunk, E);
    for (int i = e0 + threadIdx.x; i < e1; i += 1024) {
        int t = dst[i];
        if (t >= base && t < hi) {
            int pos = atomicAdd(&cur[t - base], 1);
            col[pos] = (ushort)src[i];
        }
    }
}

// ---------------------------------------------------------------------------
// Propagate v6: XCD-SELF-PINNED feature slicing. Each block reads its real
// XCC_ID (s_getreg, m09) and claims work from the matching feature-chunk's
// atomic counter (work-stealing fallback over the other chunks guarantees
// full coverage whatever the dispatch mapping is). 4 chunks x 32 feats:
// per-XCD gather working set = 3.2 MB x-slice (+1.6 MB col) -> L2-resident.
// Item = 16 nodes (4 waves x 4 nodes). Wave layout: slot = lane>>4 (4 edge
// slots), flane = lane&15 (16 feature-pairs, one dword = 2 bf16 per lane;
// 16 lanes x 4B = one 64B line per edge). Reduce = 2 shfl rounds on 2 regs.
// BN=1 applies relu(v*sc+sh) per gathered value (bn_apply fold).
template <int BN>
__global__ __launch_bounds__(256) void propagate_xcd_k(
    const uint* __restrict__ xs32, uint* __restrict__ out32,
    const int* __restrict__ row_ptr, const ushort* __restrict__ colu,
    const float* __restrict__ dinv, int n, int G, int* __restrict__ ctr,
    const float* __restrict__ stats, const float* __restrict__ gamma,
    const float* __restrict__ beta, float inv_n) {
    __shared__ int s_item, s_c;
    if (threadIdx.x == 0) {
        uint xcd = (uint)__builtin_amdgcn_s_getreg(XCC_HWREG_ENC) & 7u;
        int pref = (int)(xcd & 3u);
        int it = -1, cc = 0;
        for (int k = 0; k < 4; ++k) {
            cc = (pref + k) & 3;
            int t = atomicAdd(&ctr[cc], 1);
            if (t < G) { it = t; break; }
        }
        s_item = it;
        s_c = cc;
    }
    __syncthreads();
    int item = s_item;
    if (item < 0) return;
    int c = s_c;

    int wave = threadIdx.x >> 6;
    int lane = threadIdx.x & 63;
    int slot = lane >> 4;                 // 4 edge slots
    int flane = lane & 15;                // feature-pair index
    int uoff = c * 16 + flane;            // dword index within 64-dword row

    float sc0, sc1, sh0, sh1;
    if (BN) {
        int f0 = c * 32 + flane * 2;
        float m0 = stats[f0] * inv_n;
        float m1 = stats[f0 + 1] * inv_n;
        float v0 = stats[128 + f0] * inv_n - m0 * m0;
        float v1 = stats[128 + f0 + 1] * inv_n - m1 * m1;
        sc0 = gamma[f0] * rsqrtf(v0 + BN_EPS);
        sc1 = gamma[f0 + 1] * rsqrtf(v1 + BN_EPS);
        sh0 = beta[f0] - m0 * sc0;
        sh1 = beta[f0 + 1] - m1 * sc1;
    }

    int base = item * 16 + wave * 4;
    #pragma unroll
    for (int t = 0; t < 4; ++t) {
        int nd = base + t;
        if (nd >= n) break;
        int s = row_ptr[nd], e = row_ptr[nd + 1];
        float a0 = 0.f, a1 = 0.f;
        int i = s + slot;
        for (; i + 4 < e; i += 8) {
            int c0 = (int)colu[i];
            int c1 = (int)colu[i + 4];
            float d0 = dinv[c0], d1 = dinv[c1];
            uint v0 = xs32[(size_t)c0 * 64 + uoff];
            uint v1 = xs32[(size_t)c1 * 64 + uoff];
            float p0 = bf_lo(v0), p1 = bf_hi(v0);
            float q0 = bf_lo(v1), q1 = bf_hi(v1);
            if (BN) {
                p0 = fmaxf(p0 * sc0 + sh0, 0.f);
                p1 = fmaxf(p1 * sc1 + sh1, 0.f);
                q0 = fmaxf(q0 * sc0 + sh0, 0.f);
                q1 = fmaxf(q1 * sc1 + sh1, 0.f);
            }
            a0 += p0 * d0 + q0 * d1;
            a1 += p1 * d0 + q1 * d1;
        }
        if (i < e) {
            int c0 = (int)colu[i];
            float d0 = dinv[c0];
            uint v0 = xs32[(size_t)c0 * 64 + uoff];
            float p0 = bf_lo(v0), p1 = bf_hi(v0);
            if (BN) {
                p0 = fmaxf(p0 * sc0 + sh0, 0.f);
                p1 = fmaxf(p1 * sc1 + sh1, 0.f);
            }
            a0 += p0 * d0;
            a1 += p1 * d0;
        }
        a0 += __shfl_xor(a0, 16, 64);
        a0 += __shfl_xor(a0, 32, 64);
        a1 += __shfl_xor(a1, 16, 64);
        a1 += __shfl_xor(a1, 32, 64);
        if (slot == 0) {
            float scl = -dinv[nd];
            out32[(size_t)nd * 64 + uoff] = pack2(a0 * scl, a1 * scl);
        }
    }
}

// ---------------------------------------------------------------------------
// MFMA dual GEMM, BM=64 (do NOT raise to 128: 391 blocks = 1.5/CU imbalance
// regressed earlier; 782 blocks ~3/CU wins). LDS columns XOR-swizzled (swz8).
// MODE 0: accumulates BN column stats (sum, sumsq); also zeroes prop2's work
// counters (ctrB). MODE 1: applies BN+ReLU to A0 (raw h) during LDS staging.
template <int MODE>
__global__ __launch_bounds__(256) void gemm_mfma_k(
    const ushort* __restrict__ A0, const ushort* __restrict__ A1,
    const ushort* __restrict__ Wt, const float* __restrict__ bias,
    ushort* __restrict__ Cb, float* __restrict__ Cmu, float* __restrict__ Cls,
    float* __restrict__ stats, int* __restrict__ ctrB, int n,
    const float* __restrict__ gamma, const float* __restrict__ beta,
    float inv_n) {
    __shared__ ushort sA[64][32];
    __shared__ ushort sW[128][32];
    __shared__ float smS[4][128];
    __shared__ float smQ[4][128];
    __shared__ float sp[256];

    int tid = threadIdx.x;
    int block_row = blockIdx.x * 64;
    int wave = tid >> 6, lane = tid & 63;
    int col_base = lane & 15;
    int quad = lane >> 4;
    int m_local = wave * 16 + col_base;

    if (MODE == 0) {
        if (blockIdx.x == 0 && tid < 16) ctrB[tid] = 0;
    }
    if (MODE == 1) {
        if (tid < 128) {
            float mean = stats[tid] * inv_n;
            float var = stats[128 + tid] * inv_n - mean * mean;
            float s = gamma[tid] * rsqrtf(var + BN_EPS);
            sp[tid] = s;
            sp[128 + tid] = beta[tid] - mean * s;
        }
        __syncthreads();
    }

    f32x4 acc[8];
    #pragma unroll
    for (int t = 0; t < 8; ++t) acc[t] = (f32x4){0.f, 0.f, 0.f, 0.f};

    for (int k0 = 0; k0 < 256; k0 += 32) {
        {
            int row = tid >> 2, g = tid & 3;
            int grow = block_row + row;
            int kc = k0 + g * 8;
            uint4 v = make_uint4(0, 0, 0, 0);
            if (grow < n) {
                const ushort* srcp = (kc < 128) ? (A0 + (size_t)grow * 128 + kc)
                                                : (A1 + (size_t)grow * 128 + (kc - 128));
                v = *(const uint4*)srcp;
                if (MODE == 1 && kc < 128) {
                    float a0 = fmaxf(bf_lo(v.x) * sp[kc + 0] + sp[128 + kc + 0], 0.f);
                    float a1 = fmaxf(bf_hi(v.x) * sp[kc + 1] + sp[128 + kc + 1], 0.f);
                    float a2 = fmaxf(bf_lo(v.y) * sp[kc + 2] + sp[128 + kc + 2], 0.f);
                    float a3 = fmaxf(bf_hi(v.y) * sp[kc + 3] + sp[128 + kc + 3], 0.f);
                    float a4 = fmaxf(bf_lo(v.z) * sp[kc + 4] + sp[128 + kc + 4], 0.f);
                    float a5 = fmaxf(bf_hi(v.z) * sp[kc + 5] + sp[128 + kc + 5], 0.f);
                    float a6 = fmaxf(bf_lo(v.w) * sp[kc + 6] + sp[128 + kc + 6], 0.f);
                    float a7 = fmaxf(bf_hi(v.w) * sp[kc + 7] + sp[128 + kc + 7], 0.f);
                    v.x = pack2(a0, a1); v.y = pack2(a2, a3);
                    v.z = pack2(a4, a5); v.w = pack2(a6, a7);
                }
            }
            *(uint4*)&sA[row][swz8(row, g)] = v;
        }
        #pragma unroll
        for (int i = tid; i < 512; i += 256) {
            int c = i >> 2, g = i & 3;
            *(uint4*)&sW[c][swz8(c, g)] = *(const uint4*)(Wt + (size_t)c * 256 + k0 + g * 8);
        }
        __syncthreads();
        bf16x8 af = *(const bf16x8*)&sA[m_local][swz8(m_local, quad)];
        #pragma unroll
        for (int t = 0; t < 8; ++t) {
            int wr = t * 16 + col_base;
            bf16x8 bfr = *(const bf16x8*)&sW[wr][swz8(wr, quad)];
            acc[t] = __builtin_amdgcn_mfma_f32_16x16x32_bf16(af, bfr, acc[t], 0, 0, 0);
        }
        __syncthreads();
    }

    int row_l = wave * 16 + quad * 4;
    #pragma unroll
    for (int t = 0; t < 8; ++t) {
        int col = t * 16 + col_base;
        float b = bias[col];
        float s = 0.f, q = 0.f;
        #pragma unroll
        for (int r = 0; r < 4; ++r) {
            int grow = block_row + row_l + r;
            if (grow < n) {
                float v = acc[t][r] + b;
                if (MODE == 0) {
                    Cb[(size_t)grow * 128 + col] = f2bf(v);
                    s += v; q += v * v;
                } else {
                    if (col < 64) Cmu[(size_t)grow * 64 + col] = v;
                    else          Cls[(size_t)grow * 64 + (col - 64)] = v;
                }
            }
        }
        if (MODE == 0) {
            s += __shfl_xor(s, 16, 64); s += __shfl_xor(s, 32, 64);
            q += __shfl_xor(q, 16, 64); q += __shfl_xor(q, 32, 64);
            if (quad == 0) { smS[wave][col] = s; smQ[wave][col] = q; }
        }
    }
    if (MODE == 0) {
        __syncthreads();
        if (tid < 128) {
            float s = smS[0][tid] + smS[1][tid] + smS[2][tid] + smS[3][tid];
            float q = smQ[0][tid] + smQ[1][tid] + smQ[2][tid] + smQ[3][tid];
            atomicAdd(&stats[tid], s);
            atomicAdd(&stats[128 + tid], q);
        }
    }
}

// ---------------------------------------------------------------------------
extern "C" void kernel_launch(void* const* d_in, const int* in_sizes, int n_in,
                              void* d_out, int out_size, void* d_ws, size_t ws_size,
                              hipStream_t stream) {
    const float* x = (const float*)d_in[0];
    const int* edge_index = (const int*)d_in[1];
    const float* W1_0 = (const float*)d_in[2];
    const float* W1_1 = (const float*)d_in[3];
    const float* b1 = (const float*)d_in[4];
    const float* gamma = (const float*)d_in[5];
    const float* beta = (const float*)d_in[6];
    const float* Wmu_0 = (const float*)d_in[7];
    const float* Wmu_1 = (const float*)d_in[8];
    const float* b_mu = (const float*)d_in[9];
    const float* Wls_0 = (const float*)d_in[10];
    const float* Wls_1 = (const float*)d_in[11];
    const float* b_ls = (const float*)d_in[12];

    const int N = in_sizes[0] / IN_C;   // 50000
    const int E = in_sizes[1] / 2;      // 800000
    const int* src = edge_index;
    const int* dst = edge_index + E;

    char* w = (char*)d_ws;
    auto alloc = [&](size_t bytes) {
        char* p = w;
        w += (bytes + 15) & ~(size_t)15;
        return p;
    };
    float* stats = (float*)alloc(256 * 4);           // zeroed by count_k
    int* ctr     = (int*)alloc(32 * 4);              // ctrA [0..15], ctrB [16..31]
    int* row_ptr = (int*)alloc((size_t)(N + 1) * 4);
    int* bsum    = (int*)alloc(256 * 4);
    float* dinv  = (float*)alloc((size_t)N * 4);
    int* cnt_dst = (int*)alloc((size_t)N * 4);
    ushort* col  = (ushort*)alloc((size_t)E * 2);              // 1.6 MB
    ushort* hsrc_part = (ushort*)alloc((size_t)CS_C * N * 2);  // 3.2 MB
    ushort* hdst_part = (ushort*)alloc((size_t)CS_C * N * 2);  // 3.2 MB
    int* offs    = (int*)alloc((size_t)CS_C * N * 4);          // 6.4 MB
    ushort* x_bf  = (ushort*)alloc((size_t)N * 128 * 2);
    ushort* xp_bf = (ushort*)alloc((size_t)N * 128 * 2);       // reused as hp
    ushort* h_bf  = (ushort*)alloc((size_t)N * 128 * 2);       // raw h (pre-BN)
    ushort* Wt1   = (ushort*)alloc(128 * 256 * 2);
    ushort* Wt2   = (ushort*)alloc(128 * 256 * 2);
    float* bias1  = (float*)alloc(128 * 4);
    float* bias2  = (float*)alloc(128 * 4);

    int* ctrA = ctr;
    int* ctrB = ctr + 16;

    float* out_mu = (float*)d_out;
    float* out_ls = out_mu + (size_t)N * OUT_C;

    int chunk = (E + CS_C - 1) / CS_C;    // 25000
    int range = (N + CS_R - 1) / CS_R;    // 6250
    int NBLK = (N + 255) / 256;           // 196 node blocks
    int nb_hist = CS_R * CS_C;            // 256
    int nb_x = (N * 64 + 1023) / 1024;    // 3125
    int nb_w = 64;                        // 65536 weight elements
    float inv_n = 1.f / (float)N;

    hist_conv_k<<<nb_hist + nb_x + nb_w, 1024, 0, stream>>>(
        src, dst, hsrc_part, hdst_part, N, E, chunk, range, nb_hist, nb_x,
        x, x_bf, W1_0, W1_1, b1, Wmu_0, Wmu_1, b_mu, Wls_0, Wls_1, b_ls,
        Wt1, Wt2, bias1, bias2);
    count_k<<<NBLK, 256, 0, stream>>>(hsrc_part, hdst_part, dinv, cnt_dst, bsum,
                                      stats, ctrA, N);
    phase3_k<<<NBLK, 256, 0, stream>>>(cnt_dst, bsum, row_ptr, hdst_part, offs, N, NBLK);
    scatter_k<<<nb_hist, 1024, 0, stream>>>(src, dst, offs, col, N, E, chunk, range);

    int G = (N + 15) / 16;                // 3125 node-groups per chunk
    int pb = 4 * G;                       // 12500 blocks, self-scheduled
    propagate_xcd_k<0><<<pb, 256, 0, stream>>>((const uint*)x_bf, (uint*)xp_bf,
                                               row_ptr, col, dinv, N, G, ctrA,
                                               nullptr, nullptr, nullptr, 0.f);

    int gb = (N + 63) / 64;
    gemm_mfma_k<0><<<gb, 256, 0, stream>>>(x_bf, xp_bf, Wt1, bias1, h_bf,
                                           nullptr, nullptr, stats, ctrB, N,
                                           nullptr, nullptr, 0.f);

    // prop2 gathers RAW h and applies BN+ReLU in-register (bn_apply folded in)
    propagate_xcd_k<1><<<pb, 256, 0, stream>>>((const uint*)h_bf, (uint*)xp_bf,
                                               row_ptr, col, dinv, N, G, ctrB,
                                               stats, gamma, beta, inv_n);

    gemm_mfma_k<1><<<gb, 256, 0, stream>>>(h_bf, xp_bf, Wt2, bias2, nullptr,
                                           out_mu, out_ls, stats, ctrB, N,
                                           gamma, beta, inv_n);
}

// Round 7
// 303.978 us; speedup vs baseline: 1.8008x; 1.8008x over previous
//
#include <hip/hip_runtime.h>
#include <cstddef>
#include <cstdint>

static constexpr int IN_C  = 128;
static constexpr float BN_EPS = 1e-5f;
static constexpr int OUT_C = 64;

// counting-sort geometry (N=50000, E=800000)
static constexpr int CS_C = 32;        // edge chunks
static constexpr int NMAX = 50000;     // LDS histogram sizing (N == 50000)
static constexpr int NHALF = NMAX / 2; // packed uint counters

using bf16x8 = __attribute__((ext_vector_type(8))) short;
using f32x4  = __attribute__((ext_vector_type(4))) float;

__device__ __forceinline__ ushort f2bf(float f) {
    uint u = __float_as_uint(f);
    u += 0x7fffu + ((u >> 16) & 1u);
    return (ushort)(u >> 16);
}
__device__ __forceinline__ uint pack2(float a, float b) {
    return (uint)f2bf(a) | ((uint)f2bf(b) << 16);
}
__device__ __forceinline__ float bf_lo(uint v) { return __uint_as_float(v << 16); }
__device__ __forceinline__ float bf_hi(uint v) { return __uint_as_float(v & 0xffff0000u); }

// LDS bank-conflict-avoiding column swizzle for [row][4 groups of 8 bf16].
__device__ __forceinline__ int swz8(int row, int g) { return (g ^ ((row >> 1) & 3)) * 8; }

// ---------------------------------------------------------------------------
// K1: whole-chunk LDS histograms (packed ushort counters, 100 KB LDS).
// Each edge array is read exactly ONCE chip-wide (was 8x: once per range).
// bid<32: src-hist of chunk bid. bid in [32,64): dst-hist of chunk bid-32.
// Tail blocks: x -> x_bf convert, weight transpose/convert.
__global__ __launch_bounds__(1024) void hist_conv_k(
    const int* __restrict__ src, const int* __restrict__ dst,
    ushort* __restrict__ hsrc_part, ushort* __restrict__ hdst_part,
    int N, int E, int chunk, int nb_x,
    const float* __restrict__ x, ushort* __restrict__ xb,
    const float* __restrict__ W1_0, const float* __restrict__ W1_1,
    const float* __restrict__ b1,
    const float* __restrict__ Wmu_0, const float* __restrict__ Wmu_1,
    const float* __restrict__ b_mu,
    const float* __restrict__ Wls_0, const float* __restrict__ Wls_1,
    const float* __restrict__ b_ls,
    ushort* __restrict__ Wt1, ushort* __restrict__ Wt2,
    float* __restrict__ bias1, float* __restrict__ bias2) {
    __shared__ uint hp[NHALF];
    int bid = blockIdx.x;
    int tid = threadIdx.x;
    if (bid < 2 * CS_C) {
        bool is_dst = (bid >= CS_C);
        int c = is_dst ? bid - CS_C : bid;
        const int* ea = is_dst ? dst : src;
        ushort* outp = is_dst ? hdst_part : hsrc_part;
        for (int j = tid; j < NHALF; j += 1024) hp[j] = 0u;
        __syncthreads();
        int e0 = c * chunk, e1 = min(e0 + chunk, E);
        for (int i = e0 + tid; i < e1; i += 1024) {
            int s = ea[i];
            atomicAdd(&hp[s >> 1], 1u << ((s & 1) * 16));
        }
        __syncthreads();
        uint* op = (uint*)(outp + (size_t)c * N);   // N even -> aligned
        for (int j = tid; j < N / 2; j += 1024) op[j] = hp[j];
    } else if (bid < 2 * CS_C + nb_x) {
        int i = (bid - 2 * CS_C) * 1024 + tid;      // over N*64 float2
        if (i < N * 64) {
            float2 v = ((const float2*)x)[i];
            ((uint*)xb)[i] = pack2(v.x, v.y);
        }
    } else {
        int idx = (bid - 2 * CS_C - nb_x) * 1024 + tid;  // 65536 weights
        int which = idx >> 15;
        int c = (idx >> 8) & 127;
        int k = idx & 255;
        if (which == 0) {
            float v = (k < 128) ? W1_0[k * 128 + c] : W1_1[(k - 128) * 128 + c];
            Wt1[c * 256 + k] = f2bf(v);
            if (k == 0) bias1[c] = b1[c];
        } else {
            float v;
            if (c < 64) v = (k < 128) ? Wmu_0[k * 64 + c] : Wmu_1[(k - 128) * 64 + c];
            else        v = (k < 128) ? Wls_0[k * 64 + (c - 64)] : Wls_1[(k - 128) * 64 + (c - 64)];
            Wt2[c * 256 + k] = f2bf(v);
            if (k == 0) bias2[c] = (c < 64) ? b_mu[c] : b_ls[c - 64];
        }
    }
}

// K2: full-chip reduce over chunks -> dinv, cnt_dst, per-block sums.
__global__ __launch_bounds__(256) void count_k(
    const ushort* __restrict__ hsrc_part, const ushort* __restrict__ hdst_part,
    float* __restrict__ dinv, int* __restrict__ cnt_dst,
    int* __restrict__ bsum, float* __restrict__ stats, int N) {
    __shared__ int sw[4];
    int tid = threadIdx.x;
    if (blockIdx.x == 0) stats[tid] = 0.f;   // 256 floats
    int v = blockIdx.x * 256 + tid;
    int b = 0;
    if (v < N) {
        int a = 0;
        for (int c = 0; c < CS_C; ++c) {
            a += hsrc_part[(size_t)c * N + v];
            b += hdst_part[(size_t)c * N + v];
        }
        dinv[v] = (a > 0) ? rsqrtf((float)a) : 0.f;
        cnt_dst[v] = b;
    }
    int t = b;
    #pragma unroll
    for (int off = 1; off < 64; off <<= 1) t += __shfl_xor(t, off, 64);
    if ((tid & 63) == 0) sw[tid >> 6] = t;
    __syncthreads();
    if (tid == 0) bsum[blockIdx.x] = sw[0] + sw[1] + sw[2] + sw[3];
}

// K3: row_ptr + scatter offsets. Each block recomputes its own exclusive
// prefix over bsum (nb<=256 ints) -- absorbs a dedicated scan launch.
__global__ __launch_bounds__(256) void phase3_k(
    const int* __restrict__ cnt, const int* __restrict__ bsum,
    int* __restrict__ row_ptr, const ushort* __restrict__ hdst_part,
    int* __restrict__ offs, int n, int nb) {
    __shared__ int sbp[4];
    __shared__ int swv[4];
    int tid = threadIdx.x;
    int lane = tid & 63, wave = tid >> 6;
    int bv = (tid < nb && tid < (int)blockIdx.x) ? bsum[tid] : 0;
    int t = bv;
    #pragma unroll
    for (int off = 1; off < 64; off <<= 1) t += __shfl_xor(t, off, 64);
    if (lane == 0) sbp[wave] = t;
    int v = blockIdx.x * 256 + tid;
    int c = (v < n) ? cnt[v] : 0;
    int s = c;
    #pragma unroll
    for (int off = 1; off < 64; off <<= 1) {
        int u = __shfl_up(s, off, 64);
        if (lane >= off) s += u;
    }
    if (lane == 63) swv[wave] = s;
    __syncthreads();
    int bpre = sbp[0] + sbp[1] + sbp[2] + sbp[3];
    int wexcl = 0;
    for (int w = 0; w < wave; ++w) wexcl += swv[w];
    int st = bpre + wexcl + (s - c);   // global exclusive prefix
    if (v < n) row_ptr[v + 1] = st + c;
    if (v == 0) row_ptr[0] = 0;
    int r = st;
    for (int ch = 0; ch < CS_C; ++ch) {
        size_t idx = (size_t)ch * n + v;
        if (v < n) {
            offs[idx] = r;
            r += hdst_part[idx];
        }
    }
}

// K4: whole-chunk scatter. LDS packed delta counters + L2-resident 200 KB
// offs slice; edge arrays read exactly once chip-wide. col as ushort.
__global__ __launch_bounds__(1024) void scatter_k(
    const int* __restrict__ src, const int* __restrict__ dst,
    const int* __restrict__ offs, ushort* __restrict__ col,
    int N, int E, int chunk) {
    __shared__ uint dp[NHALF];
    int tid = threadIdx.x;
    int c = blockIdx.x;
    for (int j = tid; j < NHALF; j += 1024) dp[j] = 0u;
    __syncthreads();
    const int* offc = offs + (size_t)c * N;
    int e0 = c * chunk, e1 = min(e0 + chunk, E);
    for (int i = e0 + tid; i < e1; i += 1024) {
        int t = dst[i];
        int s = src[i];
        uint d = atomicAdd(&dp[t >> 1], 1u << ((t & 1) * 16));
        uint delta = (d >> ((t & 1) * 16)) & 0xffffu;
        int pos = offc[t] + (int)delta;
        col[pos] = (ushort)s;
    }
}

// ---------------------------------------------------------------------------
// Propagate (R2-verified structure): wave per node, 4 groups x 16 lanes,
// unroll 4 (stride 4 per group). dinv[src] applied in-gather (FMA). col is
// ushort. BN=1 applies relu(v*sc+sh) per gathered value (bn_apply fold).
#define FMA8(V, D)                                                            \
  { float v0_ = bf_lo((V).x), v1_ = bf_hi((V).x), v2_ = bf_lo((V).y),         \
          v3_ = bf_hi((V).y), v4_ = bf_lo((V).z), v5_ = bf_hi((V).z),         \
          v6_ = bf_lo((V).w), v7_ = bf_hi((V).w);                             \
    if (BN) {                                                                 \
      v0_ = fmaxf(v0_ * sc[0] + sh[0], 0.f);                                  \
      v1_ = fmaxf(v1_ * sc[1] + sh[1], 0.f);                                  \
      v2_ = fmaxf(v2_ * sc[2] + sh[2], 0.f);                                  \
      v3_ = fmaxf(v3_ * sc[3] + sh[3], 0.f);                                  \
      v4_ = fmaxf(v4_ * sc[4] + sh[4], 0.f);                                  \
      v5_ = fmaxf(v5_ * sc[5] + sh[5], 0.f);                                  \
      v6_ = fmaxf(v6_ * sc[6] + sh[6], 0.f);                                  \
      v7_ = fmaxf(v7_ * sc[7] + sh[7], 0.f);                                  \
    }                                                                         \
    acc[0] += v0_ * (D); acc[1] += v1_ * (D); acc[2] += v2_ * (D);            \
    acc[3] += v3_ * (D); acc[4] += v4_ * (D); acc[5] += v5_ * (D);            \
    acc[6] += v6_ * (D); acc[7] += v7_ * (D); }

template <int BN>
__global__ __launch_bounds__(256) void propagate4_k(
    const uint4* __restrict__ xs, uint4* __restrict__ out,
    const int* __restrict__ row_ptr, const ushort* __restrict__ colu,
    const float* __restrict__ dinv, int n,
    const float* __restrict__ stats, const float* __restrict__ gamma,
    const float* __restrict__ beta, float inv_n) {
    int wid = (blockIdx.x * 256 + threadIdx.x) >> 6;
    if (wid >= n) return;
    int lane = threadIdx.x & 63;
    int g = lane >> 4, li = lane & 15;
    float sc[8], sh[8];
    if (BN) {
        // this lane always touches features li*8 .. li*8+7 of gathered rows
        #pragma unroll
        for (int j = 0; j < 8; ++j) {
            int f = li * 8 + j;
            float mean = stats[f] * inv_n;
            float var = stats[128 + f] * inv_n - mean * mean;
            float s = gamma[f] * rsqrtf(var + BN_EPS);
            sc[j] = s;
            sh[j] = beta[f] - mean * s;
        }
    }
    int s = row_ptr[wid], e = row_ptr[wid + 1];
    float acc[8];
    #pragma unroll
    for (int k = 0; k < 8; ++k) acc[k] = 0.f;
    int i = s + g;
    for (; i + 12 < e; i += 16) {
        int c0 = (int)colu[i];
        int c1 = (int)colu[i + 4];
        int c2 = (int)colu[i + 8];
        int c3 = (int)colu[i + 12];
        float d0 = dinv[c0], d1 = dinv[c1], d2 = dinv[c2], d3 = dinv[c3];
        uint4 v0 = xs[(size_t)c0 * 16 + li];
        uint4 v1 = xs[(size_t)c1 * 16 + li];
        uint4 v2 = xs[(size_t)c2 * 16 + li];
        uint4 v3 = xs[(size_t)c3 * 16 + li];
        FMA8(v0, d0); FMA8(v1, d1); FMA8(v2, d2); FMA8(v3, d3);
    }
    for (; i < e; i += 4) {
        int c0 = (int)colu[i];
        float d0 = dinv[c0];
        uint4 v0 = xs[(size_t)c0 * 16 + li];
        FMA8(v0, d0);
    }
    #pragma unroll
    for (int k = 0; k < 8; ++k) {
        acc[k] += __shfl_xor(acc[k], 16, 64);
        acc[k] += __shfl_xor(acc[k], 32, 64);
    }
    if (g == 0) {
        float scl = -dinv[wid];
        uint4 o;
        o.x = pack2(acc[0] * scl, acc[1] * scl);
        o.y = pack2(acc[2] * scl, acc[3] * scl);
        o.z = pack2(acc[4] * scl, acc[5] * scl);
        o.w = pack2(acc[6] * scl, acc[7] * scl);
        out[(size_t)wid * 16 + li] = o;
    }
}

// ---------------------------------------------------------------------------
// MFMA dual GEMM, BM=64 (do NOT raise to 128: 391 blocks = 1.5/CU imbalance
// regressed earlier; 782 blocks ~3/CU wins). LDS columns XOR-swizzled (swz8).
// MODE 0: accumulates BN column stats (sum, sumsq) from fp32 acc.
// MODE 1: applies BN+ReLU to the A0 (raw h) operand during LDS staging.
template <int MODE>
__global__ __launch_bounds__(256) void gemm_mfma_k(
    const ushort* __restrict__ A0, const ushort* __restrict__ A1,
    const ushort* __restrict__ Wt, const float* __restrict__ bias,
    ushort* __restrict__ Cb, float* __restrict__ Cmu, float* __restrict__ Cls,
    float* __restrict__ stats, int n,
    const float* __restrict__ gamma, const float* __restrict__ beta,
    float inv_n) {
    __shared__ ushort sA[64][32];
    __shared__ ushort sW[128][32];
    __shared__ float smS[4][128];
    __shared__ float smQ[4][128];
    __shared__ float sp[256];

    int tid = threadIdx.x;
    int block_row = blockIdx.x * 64;
    int wave = tid >> 6, lane = tid & 63;
    int col_base = lane & 15;
    int quad = lane >> 4;
    int m_local = wave * 16 + col_base;

    if (MODE == 1) {
        if (tid < 128) {
            float mean = stats[tid] * inv_n;
            float var = stats[128 + tid] * inv_n - mean * mean;
            float s = gamma[tid] * rsqrtf(var + BN_EPS);
            sp[tid] = s;
            sp[128 + tid] = beta[tid] - mean * s;
        }
        __syncthreads();
    }

    f32x4 acc[8];
    #pragma unroll
    for (int t = 0; t < 8; ++t) acc[t] = (f32x4){0.f, 0.f, 0.f, 0.f};

    for (int k0 = 0; k0 < 256; k0 += 32) {
        {
            int row = tid >> 2, g = tid & 3;
            int grow = block_row + row;
            int kc = k0 + g * 8;
            uint4 v = make_uint4(0, 0, 0, 0);
            if (grow < n) {
                const ushort* srcp = (kc < 128) ? (A0 + (size_t)grow * 128 + kc)
                                                : (A1 + (size_t)grow * 128 + (kc - 128));
                v = *(const uint4*)srcp;
                if (MODE == 1 && kc < 128) {
                    float a0 = fmaxf(bf_lo(v.x) * sp[kc + 0] + sp[128 + kc + 0], 0.f);
                    float a1 = fmaxf(bf_hi(v.x) * sp[kc + 1] + sp[128 + kc + 1], 0.f);
                    float a2 = fmaxf(bf_lo(v.y) * sp[kc + 2] + sp[128 + kc + 2], 0.f);
                    float a3 = fmaxf(bf_hi(v.y) * sp[kc + 3] + sp[128 + kc + 3], 0.f);
                    float a4 = fmaxf(bf_lo(v.z) * sp[kc + 4] + sp[128 + kc + 4], 0.f);
                    float a5 = fmaxf(bf_hi(v.z) * sp[kc + 5] + sp[128 + kc + 5], 0.f);
                    float a6 = fmaxf(bf_lo(v.w) * sp[kc + 6] + sp[128 + kc + 6], 0.f);
                    float a7 = fmaxf(bf_hi(v.w) * sp[kc + 7] + sp[128 + kc + 7], 0.f);
                    v.x = pack2(a0, a1); v.y = pack2(a2, a3);
                    v.z = pack2(a4, a5); v.w = pack2(a6, a7);
                }
            }
            *(uint4*)&sA[row][swz8(row, g)] = v;
        }
        #pragma unroll
        for (int i = tid; i < 512; i += 256) {
            int c = i >> 2, g = i & 3;
            *(uint4*)&sW[c][swz8(c, g)] = *(const uint4*)(Wt + (size_t)c * 256 + k0 + g * 8);
        }
        __syncthreads();
        bf16x8 af = *(const bf16x8*)&sA[m_local][swz8(m_local, quad)];
        #pragma unroll
        for (int t = 0; t < 8; ++t) {
            int wr = t * 16 + col_base;
            bf16x8 bfr = *(const bf16x8*)&sW[wr][swz8(wr, quad)];
            acc[t] = __builtin_amdgcn_mfma_f32_16x16x32_bf16(af, bfr, acc[t], 0, 0, 0);
        }
        __syncthreads();
    }

    int row_l = wave * 16 + quad * 4;
    #pragma unroll
    for (int t = 0; t < 8; ++t) {
        int col = t * 16 + col_base;
        float b = bias[col];
        float s = 0.f, q = 0.f;
        #pragma unroll
        for (int r = 0; r < 4; ++r) {
            int grow = block_row + row_l + r;
            if (grow < n) {
                float v = acc[t][r] + b;
                if (MODE == 0) {
                    Cb[(size_t)grow * 128 + col] = f2bf(v);
                    s += v; q += v * v;
                } else {
                    if (col < 64) Cmu[(size_t)grow * 64 + col] = v;
                    else          Cls[(size_t)grow * 64 + (col - 64)] = v;
                }
            }
        }
        if (MODE == 0) {
            s += __shfl_xor(s, 16, 64); s += __shfl_xor(s, 32, 64);
            q += __shfl_xor(q, 16, 64); q += __shfl_xor(q, 32, 64);
            if (quad == 0) { smS[wave][col] = s; smQ[wave][col] = q; }
        }
    }
    if (MODE == 0) {
        __syncthreads();
        if (tid < 128) {
            float s = smS[0][tid] + smS[1][tid] + smS[2][tid] + smS[3][tid];
            float q = smQ[0][tid] + smQ[1][tid] + smQ[2][tid] + smQ[3][tid];
            atomicAdd(&stats[tid], s);
            atomicAdd(&stats[128 + tid], q);
        }
    }
}

// ---------------------------------------------------------------------------
extern "C" void kernel_launch(void* const* d_in, const int* in_sizes, int n_in,
                              void* d_out, int out_size, void* d_ws, size_t ws_size,
                              hipStream_t stream) {
    const float* x = (const float*)d_in[0];
    const int* edge_index = (const int*)d_in[1];
    const float* W1_0 = (const float*)d_in[2];
    const float* W1_1 = (const float*)d_in[3];
    const float* b1 = (const float*)d_in[4];
    const float* gamma = (const float*)d_in[5];
    const float* beta = (const float*)d_in[6];
    const float* Wmu_0 = (const float*)d_in[7];
    const float* Wmu_1 = (const float*)d_in[8];
    const float* b_mu = (const float*)d_in[9];
    const float* Wls_0 = (const float*)d_in[10];
    const float* Wls_1 = (const float*)d_in[11];
    const float* b_ls = (const float*)d_in[12];

    const int N = in_sizes[0] / IN_C;   // 50000
    const int E = in_sizes[1] / 2;      // 800000
    const int* src = edge_index;
    const int* dst = edge_index + E;

    char* w = (char*)d_ws;
    auto alloc = [&](size_t bytes) {
        char* p = w;
        w += (bytes + 15) & ~(size_t)15;
        return p;
    };
    float* stats = (float*)alloc(256 * 4);           // zeroed by count_k
    int* row_ptr = (int*)alloc((size_t)(N + 1) * 4);
    int* bsum    = (int*)alloc(256 * 4);
    float* dinv  = (float*)alloc((size_t)N * 4);
    int* cnt_dst = (int*)alloc((size_t)N * 4);
    ushort* col  = (ushort*)alloc((size_t)E * 2);              // 1.6 MB
    ushort* hsrc_part = (ushort*)alloc((size_t)CS_C * N * 2);  // 3.2 MB
    ushort* hdst_part = (ushort*)alloc((size_t)CS_C * N * 2);  // 3.2 MB
    int* offs    = (int*)alloc((size_t)CS_C * N * 4);          // 6.4 MB
    ushort* x_bf  = (ushort*)alloc((size_t)N * 128 * 2);
    ushort* xp_bf = (ushort*)alloc((size_t)N * 128 * 2);       // reused as hp
    ushort* h_bf  = (ushort*)alloc((size_t)N * 128 * 2);       // raw h (pre-BN)
    ushort* Wt1   = (ushort*)alloc(128 * 256 * 2);
    ushort* Wt2   = (ushort*)alloc(128 * 256 * 2);
    float* bias1  = (float*)alloc(128 * 4);
    float* bias2  = (float*)alloc(128 * 4);

    float* out_mu = (float*)d_out;
    float* out_ls = out_mu + (size_t)N * OUT_C;

    int chunk = (E + CS_C - 1) / CS_C;    // 25000
    int NBLK = (N + 255) / 256;           // 196 node blocks
    int nb_x = (N * 64 + 1023) / 1024;    // 3125
    int nb_w = 64;                        // 65536 weight elements
    float inv_n = 1.f / (float)N;

    hist_conv_k<<<2 * CS_C + nb_x + nb_w, 1024, 0, stream>>>(
        src, dst, hsrc_part, hdst_part, N, E, chunk, nb_x,
        x, x_bf, W1_0, W1_1, b1, Wmu_0, Wmu_1, b_mu, Wls_0, Wls_1, b_ls,
        Wt1, Wt2, bias1, bias2);
    count_k<<<NBLK, 256, 0, stream>>>(hsrc_part, hdst_part, dinv, cnt_dst, bsum, stats, N);
    phase3_k<<<NBLK, 256, 0, stream>>>(cnt_dst, bsum, row_ptr, hdst_part, offs, N, NBLK);
    scatter_k<<<CS_C, 1024, 0, stream>>>(src, dst, offs, col, N, E, chunk);

    int pb = (N + 3) / 4;                 // 12500 blocks, wave per node
    propagate4_k<0><<<pb, 256, 0, stream>>>((const uint4*)x_bf, (uint4*)xp_bf,
                                            row_ptr, col, dinv, N,
                                            nullptr, nullptr, nullptr, 0.f);

    int gb = (N + 63) / 64;
    gemm_mfma_k<0><<<gb, 256, 0, stream>>>(x_bf, xp_bf, Wt1, bias1, h_bf,
                                           nullptr, nullptr, stats, N,
                                           nullptr, nullptr, 0.f);

    // prop2 gathers RAW h and applies BN+ReLU in-register (bn_apply folded in)
    propagate4_k<1><<<pb, 256, 0, stream>>>((const uint4*)h_bf, (uint4*)xp_bf,
                                            row_ptr, col, dinv, N,
                                            stats, gamma, beta, inv_n);

    gemm_mfma_k<1><<<gb, 256, 0, stream>>>(h_bf, xp_bf, Wt2, bias2, nullptr,
                                           out_mu, out_ls, stats, N,
                                           gamma, beta, inv_n);
}

// Round 8
// 278.874 us; speedup vs baseline: 1.9629x; 1.0900x over previous
//
#include <hip/hip_runtime.h>
#include <cstddef>
#include <cstdint>

static constexpr int IN_C  = 128;
static constexpr float BN_EPS = 1e-5f;
static constexpr int OUT_C = 64;

// counting-sort geometry (N=50000, E=800000)
static constexpr int CS_C = 32;        // edge chunks
static constexpr int CS_R = 8;         // node ranges (scatter)
static constexpr int CS_RANGE = 6250;  // max nodes per range
static constexpr int NMAX = 50000;     // LDS histogram sizing (N == 50000)
static constexpr int NHALF = NMAX / 2; // packed uint counters

using bf16x8 = __attribute__((ext_vector_type(8))) short;
using f32x4  = __attribute__((ext_vector_type(4))) float;

__device__ __forceinline__ ushort f2bf(float f) {
    uint u = __float_as_uint(f);
    u += 0x7fffu + ((u >> 16) & 1u);
    return (ushort)(u >> 16);
}
__device__ __forceinline__ uint pack2(float a, float b) {
    return (uint)f2bf(a) | ((uint)f2bf(b) << 16);
}
__device__ __forceinline__ float bf_lo(uint v) { return __uint_as_float(v << 16); }
__device__ __forceinline__ float bf_hi(uint v) { return __uint_as_float(v & 0xffff0000u); }

// LDS bank-conflict-avoiding column swizzle for [row][4 groups of 8 bf16].
__device__ __forceinline__ int swz8(int row, int g) { return (g ^ ((row >> 1) & 3)) * 8; }

// ---------------------------------------------------------------------------
// K1: whole-chunk LDS histograms (packed ushort counters, 100 KB LDS) --
// edge arrays read exactly once chip-wide; co-scheduled with convert blocks.
__global__ __launch_bounds__(1024) void hist_conv_k(
    const int* __restrict__ src, const int* __restrict__ dst,
    ushort* __restrict__ hsrc_part, ushort* __restrict__ hdst_part,
    int N, int E, int chunk, int nb_x,
    const float* __restrict__ x, ushort* __restrict__ xb,
    const float* __restrict__ W1_0, const float* __restrict__ W1_1,
    const float* __restrict__ b1,
    const float* __restrict__ Wmu_0, const float* __restrict__ Wmu_1,
    const float* __restrict__ b_mu,
    const float* __restrict__ Wls_0, const float* __restrict__ Wls_1,
    const float* __restrict__ b_ls,
    ushort* __restrict__ Wt1, ushort* __restrict__ Wt2,
    float* __restrict__ bias1, float* __restrict__ bias2) {
    __shared__ uint hp[NHALF];
    int bid = blockIdx.x;
    int tid = threadIdx.x;
    if (bid < 2 * CS_C) {
        bool is_dst = (bid >= CS_C);
        int c = is_dst ? bid - CS_C : bid;
        const int* ea = is_dst ? dst : src;
        ushort* outp = is_dst ? hdst_part : hsrc_part;
        for (int j = tid; j < NHALF; j += 1024) hp[j] = 0u;
        __syncthreads();
        int e0 = c * chunk, e1 = min(e0 + chunk, E);
        for (int i = e0 + tid; i < e1; i += 1024) {
            int s = ea[i];
            atomicAdd(&hp[s >> 1], 1u << ((s & 1) * 16));
        }
        __syncthreads();
        uint* op = (uint*)(outp + (size_t)c * N);   // N even -> aligned
        for (int j = tid; j < N / 2; j += 1024) op[j] = hp[j];
    } else if (bid < 2 * CS_C + nb_x) {
        int i = (bid - 2 * CS_C) * 1024 + tid;      // over N*64 float2
        if (i < N * 64) {
            float2 v = ((const float2*)x)[i];
            ((uint*)xb)[i] = pack2(v.x, v.y);
        }
    } else {
        int idx = (bid - 2 * CS_C - nb_x) * 1024 + tid;  // 65536 weights
        int which = idx >> 15;
        int c = (idx >> 8) & 127;
        int k = idx & 255;
        if (which == 0) {
            float v = (k < 128) ? W1_0[k * 128 + c] : W1_1[(k - 128) * 128 + c];
            Wt1[c * 256 + k] = f2bf(v);
            if (k == 0) bias1[c] = b1[c];
        } else {
            float v;
            if (c < 64) v = (k < 128) ? Wmu_0[k * 64 + c] : Wmu_1[(k - 128) * 64 + c];
            else        v = (k < 128) ? Wls_0[k * 64 + (c - 64)] : Wls_1[(k - 128) * 64 + (c - 64)];
            Wt2[c * 256 + k] = f2bf(v);
            if (k == 0) bias2[c] = (c < 64) ? b_mu[c] : b_ls[c - 64];
        }
    }
}

// K2: full-chip reduce over chunks -> dinv, cnt_dst, per-block sums.
__global__ __launch_bounds__(256) void count_k(
    const ushort* __restrict__ hsrc_part, const ushort* __restrict__ hdst_part,
    float* __restrict__ dinv, int* __restrict__ cnt_dst,
    int* __restrict__ bsum, float* __restrict__ stats, int N) {
    __shared__ int sw[4];
    int tid = threadIdx.x;
    if (blockIdx.x == 0) stats[tid] = 0.f;   // 256 floats
    int v = blockIdx.x * 256 + tid;
    int b = 0;
    if (v < N) {
        int a = 0;
        for (int c = 0; c < CS_C; ++c) {
            a += hsrc_part[(size_t)c * N + v];
            b += hdst_part[(size_t)c * N + v];
        }
        dinv[v] = (a > 0) ? rsqrtf((float)a) : 0.f;
        cnt_dst[v] = b;
    }
    int t = b;
    #pragma unroll
    for (int off = 1; off < 64; off <<= 1) t += __shfl_xor(t, off, 64);
    if ((tid & 63) == 0) sw[tid >> 6] = t;
    __syncthreads();
    if (tid == 0) bsum[blockIdx.x] = sw[0] + sw[1] + sw[2] + sw[3];
}

// K3: row_ptr + scatter offsets. Each block recomputes its own exclusive
// prefix over bsum (nb<=256 ints) -- absorbs a dedicated scan launch.
__global__ __launch_bounds__(256) void phase3_k(
    const int* __restrict__ cnt, const int* __restrict__ bsum,
    int* __restrict__ row_ptr, const ushort* __restrict__ hdst_part,
    int* __restrict__ offs, int n, int nb) {
    __shared__ int sbp[4];
    __shared__ int swv[4];
    int tid = threadIdx.x;
    int lane = tid & 63, wave = tid >> 6;
    int bv = (tid < nb && tid < (int)blockIdx.x) ? bsum[tid] : 0;
    int t = bv;
    #pragma unroll
    for (int off = 1; off < 64; off <<= 1) t += __shfl_xor(t, off, 64);
    if (lane == 0) sbp[wave] = t;
    int v = blockIdx.x * 256 + tid;
    int c = (v < n) ? cnt[v] : 0;
    int s = c;
    #pragma unroll
    for (int off = 1; off < 64; off <<= 1) {
        int u = __shfl_up(s, off, 64);
        if (lane >= off) s += u;
    }
    if (lane == 63) swv[wave] = s;
    __syncthreads();
    int bpre = sbp[0] + sbp[1] + sbp[2] + sbp[3];
    int wexcl = 0;
    for (int w = 0; w < wave; ++w) wexcl += swv[w];
    int st = bpre + wexcl + (s - c);   // global exclusive prefix
    if (v < n) row_ptr[v + 1] = st + c;
    if (v == 0) row_ptr[0] = 0;
    int r = st;
    for (int ch = 0; ch < CS_C; ++ch) {
        size_t idx = (size_t)ch * n + v;
        if (v < n) {
            offs[idx] = r;
            r += hdst_part[idx];
        }
    }
}

// K4: scatter via LDS cursors, 2D (range x chunk) grid = 256 blocks
// (full-chip parallel; R5/R6-verified). col stored as ushort.
__global__ __launch_bounds__(1024) void scatter_k(
    const int* __restrict__ src, const int* __restrict__ dst,
    const int* __restrict__ off, ushort* __restrict__ col,
    int N, int E, int chunk, int range) {
    __shared__ int cur[CS_RANGE];
    int c = blockIdx.x & (CS_C - 1);
    int r = blockIdx.x / CS_C;
    int base = r * range;
    int hi = min(base + range, N);
    int rsz = hi - base;
    for (int j = threadIdx.x; j < rsz; j += 1024)
        cur[j] = off[(size_t)c * N + base + j];
    __syncthreads();
    int e0 = c * chunk, e1 = min(e0 + chunk, E);
    for (int i = e0 + threadIdx.x; i < e1; i += 1024) {
        int t = dst[i];
        if (t >= base && t < hi) {
            int pos = atomicAdd(&cur[t - base], 1);
            col[pos] = (ushort)src[i];
        }
    }
}

// ---------------------------------------------------------------------------
// FUSED propagate + MFMA GEMM. Block b: (1) propagate its 64 nodes (R2-
// verified wave-per-node gather loop, 16 nodes/wave) into LDS xpL[64][136]
// (pad -> 2-way-max bank aliasing); (2) barrier; (3) dual GEMM with A1
// staged from xpL instead of global. Removes the xp HBM round-trip and two
// launches; co-resident blocks overlap gather-latency with MFMA phases.
// MODE 0: gather x; stats (sum,sumsq) epilogue. MODE 1: gather raw h with
// BN+ReLU fold (coeffs from sp table built from stats); A0 staged with BN.
#define FMA8(V, D)                                                            \
  { float v0_ = bf_lo((V).x), v1_ = bf_hi((V).x), v2_ = bf_lo((V).y),         \
          v3_ = bf_hi((V).y), v4_ = bf_lo((V).z), v5_ = bf_hi((V).z),         \
          v6_ = bf_lo((V).w), v7_ = bf_hi((V).w);                             \
    if (MODE == 1) {                                                          \
      v0_ = fmaxf(v0_ * sc[0] + sh[0], 0.f);                                  \
      v1_ = fmaxf(v1_ * sc[1] + sh[1], 0.f);                                  \
      v2_ = fmaxf(v2_ * sc[2] + sh[2], 0.f);                                  \
      v3_ = fmaxf(v3_ * sc[3] + sh[3], 0.f);                                  \
      v4_ = fmaxf(v4_ * sc[4] + sh[4], 0.f);                                  \
      v5_ = fmaxf(v5_ * sc[5] + sh[5], 0.f);                                  \
      v6_ = fmaxf(v6_ * sc[6] + sh[6], 0.f);                                  \
      v7_ = fmaxf(v7_ * sc[7] + sh[7], 0.f);                                  \
    }                                                                         \
    acc[0] += v0_ * (D); acc[1] += v1_ * (D); acc[2] += v2_ * (D);            \
    acc[3] += v3_ * (D); acc[4] += v4_ * (D); acc[5] += v5_ * (D);            \
    acc[6] += v6_ * (D); acc[7] += v7_ * (D); }

template <int MODE>
__global__ __launch_bounds__(256) void fused_pg_k(
    const uint4* __restrict__ xsg,     // gather source rows (16 uint4 each)
    const ushort* __restrict__ A0,     // same buffer as ushort (GEMM A first half)
    const int* __restrict__ row_ptr, const ushort* __restrict__ colu,
    const float* __restrict__ dinv,
    const ushort* __restrict__ Wt, const float* __restrict__ bias,
    ushort* __restrict__ Cb, float* __restrict__ Cmu, float* __restrict__ Cls,
    float* __restrict__ stats, int n,
    const float* __restrict__ gamma, const float* __restrict__ beta,
    float inv_n) {
    __shared__ ushort sA[64][32];
    __shared__ ushort sW[128][32];
    __shared__ ushort xpL[64][136];    // 64 prop rows, +8 pad
    __shared__ float smS[4][128];
    __shared__ float smQ[4][128];
    __shared__ float sp[256];

    int tid = threadIdx.x;
    int block_row = blockIdx.x * 64;
    int wave = tid >> 6, lane = tid & 63;

    if (MODE == 1) {
        if (tid < 128) {
            float mean = stats[tid] * inv_n;
            float var = stats[128 + tid] * inv_n - mean * mean;
            float s = gamma[tid] * rsqrtf(var + BN_EPS);
            sp[tid] = s;
            sp[128 + tid] = beta[tid] - mean * s;
        }
        __syncthreads();
    }

    // ---- phase 1: propagate this block's 64 nodes into xpL ----
    {
        int g = lane >> 4, li = lane & 15;
        float sc[8], sh[8];
        if (MODE == 1) {
            #pragma unroll
            for (int j = 0; j < 8; ++j) {
                sc[j] = sp[li * 8 + j];
                sh[j] = sp[128 + li * 8 + j];
            }
        }
        for (int t = 0; t < 16; ++t) {
            int ndl = wave * 16 + t;
            int nd = block_row + ndl;
            float acc[8];
            #pragma unroll
            for (int k = 0; k < 8; ++k) acc[k] = 0.f;
            float scl = 0.f;
            if (nd < n) {
                scl = -dinv[nd];
                int s = row_ptr[nd], e = row_ptr[nd + 1];
                int i = s + g;
                for (; i + 12 < e; i += 16) {
                    int c0 = (int)colu[i];
                    int c1 = (int)colu[i + 4];
                    int c2 = (int)colu[i + 8];
                    int c3 = (int)colu[i + 12];
                    float d0 = dinv[c0], d1 = dinv[c1];
                    float d2 = dinv[c2], d3 = dinv[c3];
                    uint4 v0 = xsg[(size_t)c0 * 16 + li];
                    uint4 v1 = xsg[(size_t)c1 * 16 + li];
                    uint4 v2 = xsg[(size_t)c2 * 16 + li];
                    uint4 v3 = xsg[(size_t)c3 * 16 + li];
                    FMA8(v0, d0); FMA8(v1, d1); FMA8(v2, d2); FMA8(v3, d3);
                }
                for (; i < e; i += 4) {
                    int c0 = (int)colu[i];
                    float d0 = dinv[c0];
                    uint4 v0 = xsg[(size_t)c0 * 16 + li];
                    FMA8(v0, d0);
                }
            }
            #pragma unroll
            for (int k = 0; k < 8; ++k) {
                acc[k] += __shfl_xor(acc[k], 16, 64);
                acc[k] += __shfl_xor(acc[k], 32, 64);
            }
            if (g == 0) {
                uint4 o;
                o.x = pack2(acc[0] * scl, acc[1] * scl);
                o.y = pack2(acc[2] * scl, acc[3] * scl);
                o.z = pack2(acc[4] * scl, acc[5] * scl);
                o.w = pack2(acc[6] * scl, acc[7] * scl);
                *(uint4*)&xpL[ndl][li * 8] = o;   // zeros for OOB rows
            }
        }
    }
    __syncthreads();

    // ---- phase 2: dual GEMM (A1 from xpL) ----
    int col_base = lane & 15;
    int quad = lane >> 4;
    int m_local = wave * 16 + col_base;

    f32x4 acc[8];
    #pragma unroll
    for (int t = 0; t < 8; ++t) acc[t] = (f32x4){0.f, 0.f, 0.f, 0.f};

    for (int k0 = 0; k0 < 256; k0 += 32) {
        {
            int row = tid >> 2, g = tid & 3;
            int grow = block_row + row;
            int kc = k0 + g * 8;
            uint4 v = make_uint4(0, 0, 0, 0);
            if (kc < 128) {
                if (grow < n) {
                    v = *(const uint4*)(A0 + (size_t)grow * 128 + kc);
                    if (MODE == 1) {
                        float a0 = fmaxf(bf_lo(v.x) * sp[kc + 0] + sp[128 + kc + 0], 0.f);
                        float a1 = fmaxf(bf_hi(v.x) * sp[kc + 1] + sp[128 + kc + 1], 0.f);
                        float a2 = fmaxf(bf_lo(v.y) * sp[kc + 2] + sp[128 + kc + 2], 0.f);
                        float a3 = fmaxf(bf_hi(v.y) * sp[kc + 3] + sp[128 + kc + 3], 0.f);
                        float a4 = fmaxf(bf_lo(v.z) * sp[kc + 4] + sp[128 + kc + 4], 0.f);
                        float a5 = fmaxf(bf_hi(v.z) * sp[kc + 5] + sp[128 + kc + 5], 0.f);
                        float a6 = fmaxf(bf_lo(v.w) * sp[kc + 6] + sp[128 + kc + 6], 0.f);
                        float a7 = fmaxf(bf_hi(v.w) * sp[kc + 7] + sp[128 + kc + 7], 0.f);
                        v.x = pack2(a0, a1); v.y = pack2(a2, a3);
                        v.z = pack2(a4, a5); v.w = pack2(a6, a7);
                    }
                }
            } else {
                v = *(const uint4*)&xpL[row][kc - 128];
            }
            *(uint4*)&sA[row][swz8(row, g)] = v;
        }
        #pragma unroll
        for (int i = tid; i < 512; i += 256) {
            int c = i >> 2, g = i & 3;
            *(uint4*)&sW[c][swz8(c, g)] = *(const uint4*)(Wt + (size_t)c * 256 + k0 + g * 8);
        }
        __syncthreads();
        bf16x8 af = *(const bf16x8*)&sA[m_local][swz8(m_local, quad)];
        #pragma unroll
        for (int t = 0; t < 8; ++t) {
            int wr = t * 16 + col_base;
            bf16x8 bfr = *(const bf16x8*)&sW[wr][swz8(wr, quad)];
            acc[t] = __builtin_amdgcn_mfma_f32_16x16x32_bf16(af, bfr, acc[t], 0, 0, 0);
        }
        __syncthreads();
    }

    int row_l = wave * 16 + quad * 4;
    #pragma unroll
    for (int t = 0; t < 8; ++t) {
        int col = t * 16 + col_base;
        float b = bias[col];
        float s = 0.f, q = 0.f;
        #pragma unroll
        for (int r = 0; r < 4; ++r) {
            int grow = block_row + row_l + r;
            if (grow < n) {
                float v = acc[t][r] + b;
                if (MODE == 0) {
                    Cb[(size_t)grow * 128 + col] = f2bf(v);
                    s += v; q += v * v;
                } else {
                    if (col < 64) Cmu[(size_t)grow * 64 + col] = v;
                    else          Cls[(size_t)grow * 64 + (col - 64)] = v;
                }
            }
        }
        if (MODE == 0) {
            s += __shfl_xor(s, 16, 64); s += __shfl_xor(s, 32, 64);
            q += __shfl_xor(q, 16, 64); q += __shfl_xor(q, 32, 64);
            if (quad == 0) { smS[wave][col] = s; smQ[wave][col] = q; }
        }
    }
    if (MODE == 0) {
        __syncthreads();
        if (tid < 128) {
            float s = smS[0][tid] + smS[1][tid] + smS[2][tid] + smS[3][tid];
            float q = smQ[0][tid] + smQ[1][tid] + smQ[2][tid] + smQ[3][tid];
            atomicAdd(&stats[tid], s);
            atomicAdd(&stats[128 + tid], q);
        }
    }
}

// ---------------------------------------------------------------------------
extern "C" void kernel_launch(void* const* d_in, const int* in_sizes, int n_in,
                              void* d_out, int out_size, void* d_ws, size_t ws_size,
                              hipStream_t stream) {
    const float* x = (const float*)d_in[0];
    const int* edge_index = (const int*)d_in[1];
    const float* W1_0 = (const float*)d_in[2];
    const float* W1_1 = (const float*)d_in[3];
    const float* b1 = (const float*)d_in[4];
    const float* gamma = (const float*)d_in[5];
    const float* beta = (const float*)d_in[6];
    const float* Wmu_0 = (const float*)d_in[7];
    const float* Wmu_1 = (const float*)d_in[8];
    const float* b_mu = (const float*)d_in[9];
    const float* Wls_0 = (const float*)d_in[10];
    const float* Wls_1 = (const float*)d_in[11];
    const float* b_ls = (const float*)d_in[12];

    const int N = in_sizes[0] / IN_C;   // 50000
    const int E = in_sizes[1] / 2;      // 800000
    const int* src = edge_index;
    const int* dst = edge_index + E;

    char* w = (char*)d_ws;
    auto alloc = [&](size_t bytes) {
        char* p = w;
        w += (bytes + 15) & ~(size_t)15;
        return p;
    };
    float* stats = (float*)alloc(256 * 4);           // zeroed by count_k
    int* row_ptr = (int*)alloc((size_t)(N + 1) * 4);
    int* bsum    = (int*)alloc(256 * 4);
    float* dinv  = (float*)alloc((size_t)N * 4);
    int* cnt_dst = (int*)alloc((size_t)N * 4);
    ushort* col  = (ushort*)alloc((size_t)E * 2);              // 1.6 MB
    ushort* hsrc_part = (ushort*)alloc((size_t)CS_C * N * 2);  // 3.2 MB
    ushort* hdst_part = (ushort*)alloc((size_t)CS_C * N * 2);  // 3.2 MB
    int* offs    = (int*)alloc((size_t)CS_C * N * 4);          // 6.4 MB
    ushort* x_bf  = (ushort*)alloc((size_t)N * 128 * 2);
    ushort* h_bf  = (ushort*)alloc((size_t)N * 128 * 2);       // raw h (pre-BN)
    ushort* Wt1   = (ushort*)alloc(128 * 256 * 2);
    ushort* Wt2   = (ushort*)alloc(128 * 256 * 2);
    float* bias1  = (float*)alloc(128 * 4);
    float* bias2  = (float*)alloc(128 * 4);

    float* out_mu = (float*)d_out;
    float* out_ls = out_mu + (size_t)N * OUT_C;

    int chunk = (E + CS_C - 1) / CS_C;    // 25000
    int range = (N + CS_R - 1) / CS_R;    // 6250
    int NBLK = (N + 255) / 256;           // 196 node blocks
    int nb_x = (N * 64 + 1023) / 1024;    // 3125
    int nb_w = 64;                        // 65536 weight elements
    float inv_n = 1.f / (float)N;

    hist_conv_k<<<2 * CS_C + nb_x + nb_w, 1024, 0, stream>>>(
        src, dst, hsrc_part, hdst_part, N, E, chunk, nb_x,
        x, x_bf, W1_0, W1_1, b1, Wmu_0, Wmu_1, b_mu, Wls_0, Wls_1, b_ls,
        Wt1, Wt2, bias1, bias2);
    count_k<<<NBLK, 256, 0, stream>>>(hsrc_part, hdst_part, dinv, cnt_dst, bsum, stats, N);
    phase3_k<<<NBLK, 256, 0, stream>>>(cnt_dst, bsum, row_ptr, hdst_part, offs, N, NBLK);
    scatter_k<<<CS_R * CS_C, 1024, 0, stream>>>(src, dst, offs, col, N, E, chunk, range);

    int gb = (N + 63) / 64;               // 782 fused blocks
    fused_pg_k<0><<<gb, 256, 0, stream>>>(
        (const uint4*)x_bf, x_bf, row_ptr, col, dinv, Wt1, bias1,
        h_bf, nullptr, nullptr, stats, N, nullptr, nullptr, 0.f);

    fused_pg_k<1><<<gb, 256, 0, stream>>>(
        (const uint4*)h_bf, h_bf, row_ptr, col, dinv, Wt2, bias2,
        nullptr, out_mu, out_ls, stats, N, gamma, beta, inv_n);
}